// Round 4
// baseline (493.152 us; speedup 1.0000x reference)
//
#include <hip/hip_runtime.h>

// l=32, m=4096, n=512 fp32. Rows (131072) independent; n strictly sequential.
//   x = (input - min) / (max - min);  w[0]=1; w[k] = w[k-1] + a/w[k-1] - b*x[k-1]
// NUMERICS: recurrence is chaotic (absmax 192 vs threshold 233) — keep the
// exact expression ((w + a/w) - b*((x-mn)/denom)), IEEE div, contract off.
//
// R1: LDS-staged tiles fixed HBM amplification (1.9GB -> 512MB). 855us.
// R2: two-stage minmax reduction (no contended atomics) + barrier-free
//     single-wave recur with reg ping-pong prefetch. 501us.
// R3: NT output stores (don't evict L3-resident input), prefetch-first
//     ordering, 2048x256 minmax grid. 492us. Top-5 = harness fills
//     (2x162us fixed); controllable ~168us vs ~128us HBM floor.
// R4 (this round): kill the remaining structural overhead.
//  (a) minmax_final was a 1-block kernel: whole-GPU bubble + 2 launch gaps.
//      Deleted. Each recur block (1 wave) redundantly reduces the 2048
//      partial pairs in its prologue (16KB L2-hot, 32 uint2/lane) while its
//      tile-0 input loads are in flight. 2 launches total.
//  (b) minmax two-stage path uses native float fminf/fmaxf (1 VALU/elem vs
//      3 for the monotone-key transform): stays cleanly memory-bound at
//      8 waves/SIMD. Key transform kept only for atomic fallback.

#define ROWS 131072
#define NCOL 512
#define BROWS 64          // rows per (single-wave) block
#define TCOLS 32          // tile width in floats
#define NTILES (NCOL / TCOLS)
#define LDS_STRIDE 33     // +1 pad: bank = (row + col) % 32 -> 2-way max (free)
#define MM_BLOCKS 2048    // minmax grid; partials = 2*MM_BLOCKS u32 in ws[2..]

typedef float vfloat4 __attribute__((ext_vector_type(4)));  // native vec for NT

__device__ __forceinline__ unsigned f2key(float f) {
    unsigned u = __float_as_uint(f);
    return (u & 0x80000000u) ? ~u : (u | 0x80000000u);  // monotone float->uint
}
__device__ __forceinline__ float key2f(unsigned k) {
    unsigned u = (k & 0x80000000u) ? (k & 0x7fffffffu) : ~k;
    return __uint_as_float(u);
}

__global__ void init_ws_kernel(unsigned* ws) {
    ws[0] = 0xFFFFFFFFu;  // min key accumulator (atomic-fallback path only)
    ws[1] = 0u;           // max key accumulator
}

// Stage 1: grid-stride scan, wave shfl-reduce, block LDS-reduce, then either
// write per-block float partial (two-stage) or one atomic key pair (fallback).
__global__ __launch_bounds__(256) void minmax_part(
        const float4* __restrict__ in, unsigned* __restrict__ ws, int n4,
        int use_atomic) {
    float mn = __uint_as_float(0x7f800000u);   // +inf
    float mx = __uint_as_float(0xff800000u);   // -inf
    int idx = blockIdx.x * blockDim.x + threadIdx.x;
    int stride = gridDim.x * blockDim.x;   // 524288: n4/stride = 32 exactly
    int i = idx;
    for (; i + 3 * stride < n4; i += 4 * stride) {
        float4 v0 = in[i];
        float4 v1 = in[i + stride];
        float4 v2 = in[i + 2 * stride];
        float4 v3 = in[i + 3 * stride];
        mn = fminf(mn, v0.x); mx = fmaxf(mx, v0.x);
        mn = fminf(mn, v0.y); mx = fmaxf(mx, v0.y);
        mn = fminf(mn, v0.z); mx = fmaxf(mx, v0.z);
        mn = fminf(mn, v0.w); mx = fmaxf(mx, v0.w);
        mn = fminf(mn, v1.x); mx = fmaxf(mx, v1.x);
        mn = fminf(mn, v1.y); mx = fmaxf(mx, v1.y);
        mn = fminf(mn, v1.z); mx = fmaxf(mx, v1.z);
        mn = fminf(mn, v1.w); mx = fmaxf(mx, v1.w);
        mn = fminf(mn, v2.x); mx = fmaxf(mx, v2.x);
        mn = fminf(mn, v2.y); mx = fmaxf(mx, v2.y);
        mn = fminf(mn, v2.z); mx = fmaxf(mx, v2.z);
        mn = fminf(mn, v2.w); mx = fmaxf(mx, v2.w);
        mn = fminf(mn, v3.x); mx = fmaxf(mx, v3.x);
        mn = fminf(mn, v3.y); mx = fmaxf(mx, v3.y);
        mn = fminf(mn, v3.z); mx = fmaxf(mx, v3.z);
        mn = fminf(mn, v3.w); mx = fmaxf(mx, v3.w);
    }
    for (; i < n4; i += stride) {   // generic tail (empty at this shape)
        float4 v = in[i];
        mn = fminf(fminf(fminf(mn, v.x), fminf(v.y, v.z)), v.w);
        mx = fmaxf(fmaxf(fmaxf(mx, v.x), fmaxf(v.y, v.z)), v.w);
    }
    // wave (64-lane) reduce
    for (int off = 32; off; off >>= 1) {
        mn = fminf(mn, __shfl_down(mn, off));
        mx = fmaxf(mx, __shfl_down(mx, off));
    }
    __shared__ float smn[4], smx[4];
    int wv = threadIdx.x >> 6;
    if ((threadIdx.x & 63) == 0) { smn[wv] = mn; smx[wv] = mx; }
    __syncthreads();
    if (threadIdx.x == 0) {
        float bm = fminf(fminf(smn[0], smn[1]), fminf(smn[2], smn[3]));
        float bx = fmaxf(fmaxf(smx[0], smx[1]), fmaxf(smx[2], smx[3]));
        if (use_atomic) {
            atomicMin(&ws[0], f2key(bm));
            atomicMax(&ws[1], f2key(bx));
        } else {
            ws[2 + 2 * blockIdx.x] = __float_as_uint(bm);
            ws[3 + 2 * blockIdx.x] = __float_as_uint(bx);
        }
    }
}

__global__ __launch_bounds__(64) void recur_kernel(
        const float* __restrict__ in,
        const float* __restrict__ alpha,
        const float* __restrict__ beta,
        const unsigned* __restrict__ ws,
        float* __restrict__ out,
        int use_partials) {
    #pragma clang fp contract(off)   // bit-match numpy: no fma fusion
    __shared__ float lds[BROWS * LDS_STRIDE];   // 8448 B

    const int tid = threadIdx.x;
    const int r0 = blockIdx.x * BROWS;

    const float4* __restrict__ in4 = (const float4*)in;
    vfloat4* __restrict__ out4 = (vfloat4*)out;

    #define LOADT(T, RR)                                                      \
        _Pragma("unroll")                                                     \
        for (int p = 0; p < 8; ++p) {                                         \
            int q = tid + p * 64;                                             \
            RR[p] = in4[(size_t)(r0 + (q >> 3)) * (NCOL / 4)                  \
                        + (T) * (TCOLS / 4) + (q & 7)];                       \
        }

    #define STAGE(RR)                                                         \
        _Pragma("unroll")                                                     \
        for (int p = 0; p < 8; ++p) {                                         \
            int q = tid + p * 64;                                             \
            float* dst = &lds[(q >> 3) * LDS_STRIDE + (q & 7) * 4];           \
            dst[0] = RR[p].x; dst[1] = RR[p].y;                               \
            dst[2] = RR[p].z; dst[3] = RR[p].w;                               \
        }

    #define COMPUTE()                                                         \
        {                                                                     \
            float* myrow = &lds[tid * LDS_STRIDE];                            \
            _Pragma("unroll")                                                 \
            for (int c = 0; c < TCOLS; ++c) {                                 \
                float x = myrow[c];                                           \
                float ov = w;                                                 \
                w = (w + a / w) - b * ((x - mn) / denom);                     \
                myrow[c] = ov;                                                \
            }                                                                 \
        }

    #define STORET(T)                                                         \
        _Pragma("unroll")                                                     \
        for (int p = 0; p < 8; ++p) {                                         \
            int q = tid + p * 64;                                             \
            const float* src = &lds[(q >> 3) * LDS_STRIDE + (q & 7) * 4];     \
            vfloat4 v;                                                        \
            v.x = src[0]; v.y = src[1]; v.z = src[2]; v.w = src[3];           \
            __builtin_nontemporal_store(                                      \
                v, &out4[(size_t)(r0 + (q >> 3)) * (NCOL / 4)                 \
                         + (T) * (TCOLS / 4) + (q & 7)]);                     \
        }

    float4 R[8], S[8];   // ping-pong prefetch registers (static indexing only)

    // Issue tile-0 loads FIRST; the min/max partial reduce below overlaps
    // their latency (16KB of L2-hot uint2 reads + wave shuffle reduce).
    LOADT(0, R);

    float mn, mx;
    if (use_partials) {
        // Redundant per-block reduce of the 2048 minmax_part partials.
        // Kernel-boundary ordering guarantees visibility; 1 wave -> shfl only.
        float pmn = __uint_as_float(0x7f800000u);
        float pmx = __uint_as_float(0xff800000u);
        const uint2* pp = (const uint2*)(ws + 2);   // 8B-aligned pairs
        #pragma unroll
        for (int j = 0; j < MM_BLOCKS / 64; ++j) {  // 32 uint2 per lane
            uint2 p = pp[tid + j * 64];
            pmn = fminf(pmn, __uint_as_float(p.x));
            pmx = fmaxf(pmx, __uint_as_float(p.y));
        }
        for (int off = 32; off; off >>= 1) {
            pmn = fminf(pmn, __shfl_down(pmn, off));
            pmx = fmaxf(pmx, __shfl_down(pmx, off));
        }
        mn = __shfl(pmn, 0);
        mx = __shfl(pmx, 0);
    } else {
        mn = key2f(ws[0]);
        mx = key2f(ws[1]);
    }
    const float denom = mx - mn;
    const float a = alpha[0];
    const float b = beta[0];

    // Single-wave block: DS ops complete in order within a wave -> no
    // barriers, no vmcnt(0) drains; loads/stores pipeline across tiles.
    // NT stores: write-once output must not evict the L3-resident input.
    float w = 1.0f;
    for (int t = 0; t < NTILES; t += 2) {
        LOADT(t + 1, S);                 // t+1 <= 15 always (NTILES=16 even)
        STAGE(R);
        COMPUTE();
        STORET(t);
        if (t + 2 < NTILES) LOADT(t + 2, R);
        STAGE(S);
        COMPUTE();
        STORET(t + 1);
    }

    #undef LOADT
    #undef STAGE
    #undef COMPUTE
    #undef STORET
}

extern "C" void kernel_launch(void* const* d_in, const int* in_sizes, int n_in,
                              void* d_out, int out_size, void* d_ws, size_t ws_size,
                              hipStream_t stream) {
    const float* in    = (const float*)d_in[0];
    const float* alpha = (const float*)d_in[1];
    const float* beta  = (const float*)d_in[2];
    float* out = (float*)d_out;
    unsigned* ws = (unsigned*)d_ws;

    const int n_elem = in_sizes[0];   // 67108864
    const int n4 = n_elem / 4;

    const bool two_stage =
        ws_size >= (size_t)(2 + 2 * MM_BLOCKS) * sizeof(unsigned);

    if (!two_stage) {
        hipLaunchKernelGGL(init_ws_kernel, dim3(1), dim3(1), 0, stream, ws);
    }
    hipLaunchKernelGGL(minmax_part, dim3(MM_BLOCKS), dim3(256), 0, stream,
                       (const float4*)in, ws, n4, two_stage ? 0 : 1);
    hipLaunchKernelGGL(recur_kernel, dim3(ROWS / BROWS), dim3(64), 0, stream,
                       in, alpha, beta, ws, out, two_stage ? 1 : 0);
}